// Round 5
// baseline (337.213 us; speedup 1.0000x reference)
//
#include <hip/hip_runtime.h>
#include <hip/hip_bf16.h>

#define NN 100000
#define BB 64
#define EE 1600000
#define FD 128
#define SLOTC 64                 // per-graph kept-row capacity (actual: 1)
#define KSLOTS (BB * SLOTC)
#define NB 128                   // grid blocks (<=256 CUs, 1/CU by LDS -> co-resident)
#define BT 512                   // threads per block
#define GS (NB * BT)

// grid-wide sense barrier. flags[] starts as 0xAAAAAAAA poison -> negative
// generation distance -> spins until a real write. Blocks only write their own
// flag; readers use agent-scope acquire loads; __threadfence = agent fence
// (buffer_wbl2/buffer_inv on gfx950) makes plain stores visible cross-XCD.
__device__ __forceinline__ void gridbar(int* flags, int gen) {
    __syncthreads();
    __threadfence();
    if (threadIdx.x == 0)
        __hip_atomic_store(&flags[blockIdx.x], gen, __ATOMIC_RELEASE, __HIP_MEMORY_SCOPE_AGENT);
    for (int j = threadIdx.x; j < NB; j += BT) {
        while ((int)((unsigned)__hip_atomic_load(&flags[j], __ATOMIC_ACQUIRE,
                                                 __HIP_MEMORY_SCOPE_AGENT) - (unsigned)gen) < 0)
            __builtin_amdgcn_s_sleep(8);
    }
    __syncthreads();
    __threadfence();
}

__global__ __launch_bounds__(BT) void k_mega(
    const float* __restrict__ x, const int* __restrict__ ei,
    const int* __restrict__ bidx, const float* __restrict__ tw,
    const float* __restrict__ W1, const float* __restrict__ b1,
    const float* __restrict__ g1, const float* __restrict__ be1,
    const float* __restrict__ rm1, const float* __restrict__ rv1,
    const float* __restrict__ W2, const float* __restrict__ b2,
    const float* __restrict__ g2, const float* __restrict__ be2,
    const float* __restrict__ rm2, const float* __restrict__ rv2,
    const float* __restrict__ W3, const float* __restrict__ b3,
    const float* __restrict__ g3, const float* __restrict__ be3,
    const float* __restrict__ rm3, const float* __restrict__ rv3,
    const float* __restrict__ linW, const float* __restrict__ linb,
    unsigned char* __restrict__ kf, int* __restrict__ nslot,
    float* __restrict__ degs, float* __restrict__ h0s,
    int* __restrict__ kedge, int* __restrict__ starts,
    int* __restrict__ kecnt, int* __restrict__ flags,
    float* __restrict__ hY, float* __restrict__ hYB,
    float* __restrict__ out)
{
    __shared__ float ftile[SLOTC * FD];   // 32 KB feature tile (h1/agg/h2/h3)
    __shared__ float red[BT];
    __shared__ float psl[SLOTC * 2];
    __shared__ float poolv[FD];
    __shared__ int   klist[SLOTC];
    __shared__ int   lcnt;
    __shared__ float shm, shs, shthr;
    __shared__ int   nkS;

    const int b = blockIdx.x, tid = threadIdx.x;
    const int gtid = b * BT + tid;

    // ---- P0a: segment starts (kills binary search), kf zero, kecnt=0 ------
    if (gtid == 0) *kecnt = 0;
    for (int i = gtid; i < NN; i += GS) kf[i] = 0;
    for (int i = gtid; i <= NN; i += GS) {
        if (i == 0) {
            int c = bidx[0];
            for (int v = 0; v <= c; v++) starts[v] = 0;
        } else if (i == NN) {
            int a = bidx[NN - 1];
            for (int v = a + 1; v <= BB; v++) starts[v] = NN;
        } else {
            int a = bidx[i - 1], c = bidx[i];
            for (int v = a + 1; v <= c; v++) starts[v] = i;
        }
    }
    gridbar(flags, 1);

    // ---- P0b: per-graph softmax + keep + slot init (blocks 0..63) ---------
    if (b < BB) {
        int s0 = starts[b], e0 = starts[b + 1], L = e0 - s0;
        float w0 = tw[0], w1 = tw[1];
        if (tid == 0) lcnt = 0;
        float mx = -3.4028235e38f;
        for (int j = tid; j < L; j += BT) {
            int i = s0 + j;
            mx = fmaxf(mx, x[2*i]*w0 + x[2*i+1]*w1);
        }
        red[tid] = mx; __syncthreads();
        for (int s = BT/2; s > 0; s >>= 1) { if (tid < s) red[tid] = fmaxf(red[tid], red[tid+s]); __syncthreads(); }
        if (tid == 0) shm = red[0];
        __syncthreads();
        float m = shm;
        float sm = 0.f;
        for (int j = tid; j < L; j += BT) {
            int i = s0 + j;
            sm += expf(x[2*i]*w0 + x[2*i+1]*w1 - m);
        }
        red[tid] = sm; __syncthreads();
        for (int s = BT/2; s > 0; s >>= 1) { if (tid < s) red[tid] += red[tid+s]; __syncthreads(); }
        if (tid == 0) shs = red[0];
        __syncthreads();
        float S = shs;
        float smx = -3.4028235e38f;
        for (int j = tid; j < L; j += BT) {
            int i = s0 + j;
            smx = fmaxf(smx, expf(x[2*i]*w0 + x[2*i+1]*w1 - m) / S);
        }
        red[tid] = smx; __syncthreads();
        for (int s = BT/2; s > 0; s >>= 1) { if (tid < s) red[tid] = fmaxf(red[tid], red[tid+s]); __syncthreads(); }
        if (tid == 0) shthr = fminf(red[0] - 1e-7f, 0.1f);
        __syncthreads();
        float thr = shthr;
        for (int j = tid; j < L; j += BT) {
            int i = s0 + j;
            float sc = expf(x[2*i]*w0 + x[2*i+1]*w1 - m) / S;
            if (sc > thr) {
                int l = atomicAdd(&lcnt, 1);
                if (l < SLOTC) klist[l] = i;
            }
        }
        __syncthreads();
        int nk = lcnt; if (nk > SLOTC) nk = SLOTC;
        if (tid == 0) nkS = nk;
        for (int l = tid; l < nk; l += BT) {
            int i = klist[l];
            float sc = expf(x[2*i]*w0 + x[2*i+1]*w1 - m) / S;
            int slot = b * SLOTC + l;
            kf[i] = 1; nslot[i] = slot;
            degs[slot] = 1.0f;                 // self-loop
            h0s[2*slot]   = x[2*i] * sc;
            h0s[2*slot+1] = x[2*i+1] * sc;
        }
    }
    gridbar(flags, 2);

    // ---- P1: edge scan (whole grid) ---------------------------------------
    for (int e = gtid; e < EE; e += GS) {
        int s = ei[e], d = ei[EE + e];
        if ((kf[s] & kf[d]) != 0) {
            atomicAdd(&degs[nslot[d]], 1.0f);
            int idx = atomicAdd(kecnt, 1);
            if (idx < EE) { kedge[2*idx] = nslot[s]; kedge[2*idx+1] = nslot[d]; }
        }
    }
    gridbar(flags, 3);

    int ke = 0;
    if (b < BB) {
        ke = __hip_atomic_load(kecnt, __ATOMIC_RELAXED, __HIP_MEMORY_SCOPE_AGENT);
        if (ke > EE) ke = EE;
    }

    // ---- P2: layer-1 agg (2-wide) + node + mm2 -> hY ----------------------
    if (b < BB) {
        int nk = nkS;
        for (int j = tid; j < SLOTC*2; j += BT) psl[j] = 0.f;
        __syncthreads();
        for (int t = tid; t < ke; t += BT) {
            int d = kedge[2*t+1];
            if ((d >> 6) == b) {
                int s = kedge[2*t], ld = d & (SLOTC-1);
                float nm = rsqrtf(degs[s]) * rsqrtf(degs[d]);
                atomicAdd(&psl[2*ld],   nm * h0s[2*s]);
                atomicAdd(&psl[2*ld+1], nm * h0s[2*s+1]);
            }
        }
        __syncthreads();
        for (int j = tid; j < nk*FD; j += BT) {
            int ld = j >> 7, f = j & 127, slot = b*SLOTC + ld;
            float di = rsqrtf(degs[slot]), d2 = di*di;
            float a0 = psl[2*ld]   + d2 * h0s[2*slot];
            float a1 = psl[2*ld+1] + d2 * h0s[2*slot+1];
            float v = a0*W1[f] + a1*W1[FD+f] + b1[f];
            v = fmaxf(v, 0.f);
            v = (v - rm1[f]) * rsqrtf(rv1[f] + 1e-5f) * g1[f] + be1[f];
            ftile[j] = v;
        }
        __syncthreads();
        for (int j = tid; j < nk*FD; j += BT) {
            int ld = j >> 7, f = j & 127;
            const float* xr = ftile + ld*FD;
            float acc = 0.f;
            #pragma unroll 8
            for (int k = 0; k < FD; k++) acc += xr[k] * W2[k*FD + f];
            hY[(size_t)(b*SLOTC + ld)*FD + f] = acc;
        }
    }
    gridbar(flags, 4);

    // ---- P3: scatter2 (filtered scan) + bn2 + mm3 -> hYB ------------------
    if (b < BB) {
        int nk = nkS;
        for (int j = tid; j < nk*FD; j += BT) ftile[j] = 0.f;
        __syncthreads();
        for (int t = tid; t < ke; t += BT) {
            int d = kedge[2*t+1];
            if ((d >> 6) == b) {
                int s = kedge[2*t], ld = d & (SLOTC-1);
                float nm = rsqrtf(degs[s]) * rsqrtf(degs[d]);
                const float* ys = hY + (size_t)s*FD;
                for (int f = 0; f < FD; f++) atomicAdd(&ftile[ld*FD+f], nm * ys[f]);
            }
        }
        __syncthreads();
        for (int j = tid; j < nk*FD; j += BT) {
            int ld = j >> 7, f = j & 127, slot = b*SLOTC + ld;
            float di = rsqrtf(degs[slot]);
            float v = ftile[j] + di*di*hY[(size_t)slot*FD+f] + b2[f];
            v = fmaxf(v, 0.f);
            v = (v - rm2[f]) * rsqrtf(rv2[f] + 1e-5f) * g2[f] + be2[f];
            ftile[j] = v;
        }
        __syncthreads();
        for (int j = tid; j < nk*FD; j += BT) {
            int ld = j >> 7, f = j & 127;
            const float* xr = ftile + ld*FD;
            float acc = 0.f;
            #pragma unroll 8
            for (int k = 0; k < FD; k++) acc += xr[k] * W3[k*FD + f];
            hYB[(size_t)(b*SLOTC + ld)*FD + f] = acc;
        }
    }
    gridbar(flags, 5);

    // ---- P4: scatter3 + bn3 + pool + linear + log_softmax -----------------
    if (b < BB) {
        int nk = nkS;
        for (int j = tid; j < nk*FD; j += BT) ftile[j] = 0.f;
        __syncthreads();
        for (int t = tid; t < ke; t += BT) {
            int d = kedge[2*t+1];
            if ((d >> 6) == b) {
                int s = kedge[2*t], ld = d & (SLOTC-1);
                float nm = rsqrtf(degs[s]) * rsqrtf(degs[d]);
                const float* ys = hYB + (size_t)s*FD;
                for (int f = 0; f < FD; f++) atomicAdd(&ftile[ld*FD+f], nm * ys[f]);
            }
        }
        __syncthreads();
        for (int j = tid; j < nk*FD; j += BT) {
            int ld = j >> 7, f = j & 127, slot = b*SLOTC + ld;
            float di = rsqrtf(degs[slot]);
            float v = ftile[j] + di*di*hYB[(size_t)slot*FD+f] + b3[f];
            v = fmaxf(v, 0.f);
            v = (v - rm3[f]) * rsqrtf(rv3[f] + 1e-5f) * g3[f] + be3[f];
            ftile[j] = v;
        }
        __syncthreads();
        for (int f = tid; f < FD; f += BT) {
            float mx = -3.4028235e38f;
            for (int ld = 0; ld < nk; ld++) mx = fmaxf(mx, ftile[ld*FD+f]);
            poolv[f] = mx;
        }
        __syncthreads();
        if (tid == 0) {
            float z0 = linb[0], z1 = linb[1], z2 = linb[2];
            for (int f = 0; f < FD; f++) {
                float pv = poolv[f];
                z0 += pv * linW[f*3+0];
                z1 += pv * linW[f*3+1];
                z2 += pv * linW[f*3+2];
            }
            float m2 = fmaxf(z0, fmaxf(z1, z2));
            float l = m2 + logf(expf(z0-m2) + expf(z1-m2) + expf(z2-m2));
            out[b*3+0] = z0 - l;
            out[b*3+1] = z1 - l;
            out[b*3+2] = z2 - l;
        }
    }
}

extern "C" void kernel_launch(void* const* d_in, const int* in_sizes, int n_in,
                              void* d_out, int out_size, void* d_ws, size_t ws_size,
                              hipStream_t stream) {
    (void)in_sizes; (void)n_in; (void)out_size; (void)ws_size;
    const float* x    = (const float*)d_in[0];
    const int*   ei   = (const int*)d_in[1];
    const int*   bidx = (const int*)d_in[2];
    const float* tw   = (const float*)d_in[3];
    const float* W1 = (const float*)d_in[4],  *b1 = (const float*)d_in[5],  *g1 = (const float*)d_in[6];
    const float* be1= (const float*)d_in[7],  *rm1= (const float*)d_in[8],  *rv1= (const float*)d_in[9];
    const float* W2 = (const float*)d_in[10], *b2 = (const float*)d_in[11], *g2 = (const float*)d_in[12];
    const float* be2= (const float*)d_in[13], *rm2= (const float*)d_in[14], *rv2= (const float*)d_in[15];
    const float* W3 = (const float*)d_in[16], *b3 = (const float*)d_in[17], *g3 = (const float*)d_in[18];
    const float* be3= (const float*)d_in[19], *rm3= (const float*)d_in[20], *rv3= (const float*)d_in[21];
    const float* linW = (const float*)d_in[22], *linb = (const float*)d_in[23];
    float* out = (float*)d_out;

    char* w = (char*)d_ws;
    auto take = [&](size_t bytes) { char* r = w; w += (bytes + 255) & ~(size_t)255; return r; };
    int*   flags = (int*)take((size_t)NB * 4);       // poisoned 0xAA = pre-gen
    int*   kecnt = (int*)take(16);
    int*   starts= (int*)take((size_t)(BB + 1) * 4);
    unsigned char* kf = (unsigned char*)take(NN);
    int*   nslot = (int*)take((size_t)NN * 4);
    float* degs  = (float*)take((size_t)KSLOTS * 4);
    float* h0s   = (float*)take((size_t)KSLOTS * 8);
    int*   kedge = (int*)take((size_t)EE * 8);       // exact capacity, no clamp loss
    float* hY    = (float*)take((size_t)KSLOTS * FD * 4);
    float* hYB   = (float*)take((size_t)KSLOTS * FD * 4);
    // ~17.5 MB total

    k_mega<<<NB, BT, 0, stream>>>(x, ei, bidx, tw,
                                  W1, b1, g1, be1, rm1, rv1,
                                  W2, b2, g2, be2, rm2, rv2,
                                  W3, b3, g3, be3, rm3, rv3,
                                  linW, linb,
                                  kf, nslot, degs, h0s, kedge, starts,
                                  kecnt, flags, hY, hYB, out);
}

// Round 6
// 149.398 us; speedup vs baseline: 2.2571x; 2.2571x over previous
//
#include <hip/hip_runtime.h>

#define NN 100000
#define BB 64
#define EE 1600000
#define FD 128
#define SLOTC 64                 // per-graph kept-row capacity (actual keep count: ~1)
#define KSLOTS (BB * SLOTC)
#define EMAXE (1 << 20)          // kedge capacity (actual: ~0-2)
#define LCAP 12288               // LDS score cache (graphs avg ~1562 nodes)

// K1: one block per graph (bidx sorted -> contiguous range). Fuses logit,
// softmax max/sum, max-score, keep threshold, per-graph slot alloc, h0/deg init.
__global__ __launch_bounds__(256) void k_scorekeep(
    const float2* __restrict__ x, const int* __restrict__ bidx,
    const float* __restrict__ tw,
    unsigned char* __restrict__ kf, int* __restrict__ nslot,
    int* __restrict__ knt, float* __restrict__ degs,
    float2* __restrict__ h0s, int* __restrict__ kecnt)
{
    __shared__ float cache[LCAP];
    __shared__ float red[256];
    __shared__ int   klist[SLOTC];
    __shared__ int   lcnt;
    __shared__ float shv;
    int b = blockIdx.x, tid = threadIdx.x;
    if (tid == 0) { lcnt = 0; if (b == 0) *kecnt = 0; }

    int lo = 0, hi = NN;                       // wave-uniform binary searches
    while (lo < hi) { int mid = (lo + hi) >> 1; if (bidx[mid] < b) lo = mid + 1; else hi = mid; }
    int s0 = lo;
    hi = NN;
    while (lo < hi) { int mid = (lo + hi) >> 1; if (bidx[mid] < b + 1) lo = mid + 1; else hi = mid; }
    int L = lo - s0;
    float w0 = tw[0], w1 = tw[1];
    bool fit = (L <= LCAP);
    __syncthreads();

    // pass 1: logits + max; zero kf over own range
    float mx = -3.4028235e38f;
    for (int j = tid; j < L; j += 256) {
        float2 v = x[s0 + j];
        float l = v.x * w0 + v.y * w1;
        if (fit) cache[j] = l;
        kf[s0 + j] = 0;
        mx = fmaxf(mx, l);
    }
    red[tid] = mx; __syncthreads();
    for (int s = 128; s > 0; s >>= 1) { if (tid < s) red[tid] = fmaxf(red[tid], red[tid + s]); __syncthreads(); }
    if (tid == 0) shv = red[0];
    __syncthreads();
    float m = shv;

    // pass 2: sum of exp
    float sm = 0.f;
    for (int j = tid; j < L; j += 256) {
        float l;
        if (fit) l = cache[j];
        else { float2 v = x[s0 + j]; l = v.x * w0 + v.y * w1; }
        float e = expf(l - m);
        if (fit) cache[j] = e;
        sm += e;
    }
    red[tid] = sm; __syncthreads();
    for (int s = 128; s > 0; s >>= 1) { if (tid < s) red[tid] += red[tid + s]; __syncthreads(); }
    if (tid == 0) shv = red[0];
    __syncthreads();
    float S = shv;

    // pass 3: max score
    float smx = -3.4028235e38f;
    for (int j = tid; j < L; j += 256) {
        float e;
        if (fit) e = cache[j];
        else { float2 v = x[s0 + j]; e = expf(v.x * w0 + v.y * w1 - m); }
        float sc = e / S;
        if (fit) cache[j] = sc;
        smx = fmaxf(smx, sc);
    }
    red[tid] = smx; __syncthreads();
    for (int s = 128; s > 0; s >>= 1) { if (tid < s) red[tid] = fmaxf(red[tid], red[tid + s]); __syncthreads(); }
    if (tid == 0) shv = fminf(red[0] - 1e-7f, 0.1f);
    __syncthreads();
    float thr = shv;

    // pass 4: claim keeps
    for (int j = tid; j < L; j += 256) {
        float sc;
        if (fit) sc = cache[j];
        else { float2 v = x[s0 + j]; sc = expf(v.x * w0 + v.y * w1 - m) / S; }
        if (sc > thr) {
            int l = atomicAdd(&lcnt, 1);
            if (l < SLOTC) klist[l] = j;
        }
    }
    __syncthreads();
    int nk = lcnt; if (nk > SLOTC) nk = SLOTC;
    if (tid == 0) knt[b] = nk;
    for (int l = tid; l < nk; l += 256) {
        int j = klist[l], i = s0 + j;
        float sc;
        if (fit) sc = cache[j];
        else { float2 v = x[i]; sc = expf(v.x * w0 + v.y * w1 - m) / S; }
        int slot = b * SLOTC + l;
        kf[i] = 1; nslot[i] = slot;
        degs[slot] = 1.0f;                     // self-loop
        float2 v = x[i];
        h0s[slot] = make_float2(v.x * sc, v.y * sc);
    }
}

// K2: full edge scan; kept-kept edges -> slot pairs + degree accumulation.
__global__ void k_edges(const int* __restrict__ ei, const unsigned char* __restrict__ kf,
                        const int* __restrict__ nslot, float* __restrict__ degs,
                        int* __restrict__ kedge, int* __restrict__ kecnt) {
    int e = blockIdx.x * 256 + threadIdx.x;
    if (e >= EE) return;
    int s = ei[e];
    if (kf[s]) {                               // rare (p ~ 6e-4): skip 2nd gather
        int d = ei[EE + e];
        if (kf[d]) {
            int ds = nslot[d];
            atomicAdd(&degs[ds], 1.0f);
            int idx = atomicAdd(kecnt, 1);
            if (idx < EMAXE) { kedge[2 * idx] = nslot[s]; kedge[2 * idx + 1] = ds; }
        }
    }
}

// T1: per-graph: layer-1 agg (2-wide) + node(BN/ReLU) in LDS + mm2 -> hY
__global__ __launch_bounds__(256) void k_tail1(
    const float* __restrict__ degs, const float2* __restrict__ h0s,
    const int* __restrict__ kedge, const int* __restrict__ kecnt,
    const int* __restrict__ knt,
    const float* __restrict__ W1, const float* __restrict__ b1,
    const float* __restrict__ g1, const float* __restrict__ be1,
    const float* __restrict__ rm1, const float* __restrict__ rv1,
    const float* __restrict__ W2, float* __restrict__ hY)
{
    __shared__ float ftile[SLOTC * FD];
    __shared__ float2 psl[SLOTC];
    __shared__ int keS, nkS;
    int b = blockIdx.x, tid = threadIdx.x;
    if (tid == 0) { int k = *kecnt; keS = k > EMAXE ? EMAXE : k; nkS = knt[b]; }
    for (int j = tid; j < SLOTC; j += 256) psl[j] = make_float2(0.f, 0.f);
    __syncthreads();
    int ke = keS, nk = nkS;
    for (int t = tid; t < ke; t += 256) {
        int d = kedge[2 * t + 1];
        if ((d >> 6) == b) {
            int s = kedge[2 * t], ld = d & 63;
            float nm = rsqrtf(degs[s]) * rsqrtf(degs[d]);
            float2 h = h0s[s];
            atomicAdd(&psl[ld].x, nm * h.x);
            atomicAdd(&psl[ld].y, nm * h.y);
        }
    }
    __syncthreads();
    for (int j = tid; j < nk * FD; j += 256) {
        int ld = j >> 7, f = j & 127, slot = b * SLOTC + ld;
        float di = rsqrtf(degs[slot]), d2 = di * di;
        float2 h = h0s[slot];
        float a0 = psl[ld].x + d2 * h.x;
        float a1 = psl[ld].y + d2 * h.y;
        float v = a0 * W1[f] + a1 * W1[FD + f] + b1[f];
        v = fmaxf(v, 0.f);
        v = (v - rm1[f]) * rsqrtf(rv1[f] + 1e-5f) * g1[f] + be1[f];
        ftile[j] = v;
    }
    __syncthreads();
    for (int j = tid; j < nk * FD; j += 256) {
        int ld = j >> 7, f = j & 127;
        const float* xr = ftile + ld * FD;
        float acc = 0.f;
        #pragma unroll 8
        for (int k = 0; k < FD; k++) acc += xr[k] * W2[k * FD + f];
        hY[(b * SLOTC + ld) * FD + f] = acc;
    }
}

// T2: per-graph: scatter(hY) + bn2 in LDS + mm3 -> hYB
__global__ __launch_bounds__(256) void k_tail2(
    const float* __restrict__ degs, const int* __restrict__ kedge,
    const int* __restrict__ kecnt, const int* __restrict__ knt,
    const float* __restrict__ hY,
    const float* __restrict__ b2, const float* __restrict__ g2,
    const float* __restrict__ be2, const float* __restrict__ rm2,
    const float* __restrict__ rv2,
    const float* __restrict__ W3, float* __restrict__ hYB)
{
    __shared__ float ftile[SLOTC * FD];
    __shared__ int keS, nkS;
    int b = blockIdx.x, tid = threadIdx.x;
    if (tid == 0) { int k = *kecnt; keS = k > EMAXE ? EMAXE : k; nkS = knt[b]; }
    __syncthreads();
    int ke = keS, nk = nkS;
    for (int j = tid; j < nk * FD; j += 256) ftile[j] = 0.f;
    __syncthreads();
    for (long long idx = tid; idx < (long long)ke * FD; idx += 256) {
        int e = (int)(idx >> 7), f = (int)(idx & 127);
        int d = kedge[2 * e + 1];
        if ((d >> 6) == b) {
            int s = kedge[2 * e];
            float nm = rsqrtf(degs[s]) * rsqrtf(degs[d]);
            atomicAdd(&ftile[(d & 63) * FD + f], nm * hY[s * FD + f]);
        }
    }
    __syncthreads();
    for (int j = tid; j < nk * FD; j += 256) {
        int ld = j >> 7, f = j & 127, slot = b * SLOTC + ld;
        float di = rsqrtf(degs[slot]);
        float v = ftile[j] + di * di * hY[slot * FD + f] + b2[f];
        v = fmaxf(v, 0.f);
        v = (v - rm2[f]) * rsqrtf(rv2[f] + 1e-5f) * g2[f] + be2[f];
        ftile[j] = v;
    }
    __syncthreads();
    for (int j = tid; j < nk * FD; j += 256) {
        int ld = j >> 7, f = j & 127;
        const float* xr = ftile + ld * FD;
        float acc = 0.f;
        #pragma unroll 8
        for (int k = 0; k < FD; k++) acc += xr[k] * W3[k * FD + f];
        hYB[(b * SLOTC + ld) * FD + f] = acc;
    }
}

// T3: per-graph: scatter(hYB) + bn3 + max-pool + linear + log_softmax -> out
__global__ __launch_bounds__(256) void k_tail3(
    const float* __restrict__ degs, const int* __restrict__ kedge,
    const int* __restrict__ kecnt, const int* __restrict__ knt,
    const float* __restrict__ hYB,
    const float* __restrict__ b3, const float* __restrict__ g3,
    const float* __restrict__ be3, const float* __restrict__ rm3,
    const float* __restrict__ rv3,
    const float* __restrict__ linW, const float* __restrict__ linb,
    float* __restrict__ out)
{
    __shared__ float ftile[SLOTC * FD];
    __shared__ float poolv[FD];
    __shared__ int keS, nkS;
    int b = blockIdx.x, tid = threadIdx.x;
    if (tid == 0) { int k = *kecnt; keS = k > EMAXE ? EMAXE : k; nkS = knt[b]; }
    __syncthreads();
    int ke = keS, nk = nkS;
    for (int j = tid; j < nk * FD; j += 256) ftile[j] = 0.f;
    __syncthreads();
    for (long long idx = tid; idx < (long long)ke * FD; idx += 256) {
        int e = (int)(idx >> 7), f = (int)(idx & 127);
        int d = kedge[2 * e + 1];
        if ((d >> 6) == b) {
            int s = kedge[2 * e];
            float nm = rsqrtf(degs[s]) * rsqrtf(degs[d]);
            atomicAdd(&ftile[(d & 63) * FD + f], nm * hYB[s * FD + f]);
        }
    }
    __syncthreads();
    for (int j = tid; j < nk * FD; j += 256) {
        int ld = j >> 7, f = j & 127, slot = b * SLOTC + ld;
        float di = rsqrtf(degs[slot]);
        float v = ftile[j] + di * di * hYB[slot * FD + f] + b3[f];
        v = fmaxf(v, 0.f);
        v = (v - rm3[f]) * rsqrtf(rv3[f] + 1e-5f) * g3[f] + be3[f];
        ftile[j] = v;
    }
    __syncthreads();
    for (int f = tid; f < FD; f += 256) {
        float mx = -3.4028235e38f;
        for (int ld = 0; ld < nk; ld++) mx = fmaxf(mx, ftile[ld * FD + f]);
        poolv[f] = mx;
    }
    __syncthreads();
    if (tid == 0) {
        float z0 = linb[0], z1 = linb[1], z2 = linb[2];
        for (int f = 0; f < FD; f++) {
            float pv = poolv[f];
            z0 += pv * linW[f * 3 + 0];
            z1 += pv * linW[f * 3 + 1];
            z2 += pv * linW[f * 3 + 2];
        }
        float m = fmaxf(z0, fmaxf(z1, z2));
        float l = m + logf(expf(z0 - m) + expf(z1 - m) + expf(z2 - m));
        out[b * 3 + 0] = z0 - l;
        out[b * 3 + 1] = z1 - l;
        out[b * 3 + 2] = z2 - l;
    }
}

extern "C" void kernel_launch(void* const* d_in, const int* in_sizes, int n_in,
                              void* d_out, int out_size, void* d_ws, size_t ws_size,
                              hipStream_t stream) {
    (void)in_sizes; (void)n_in; (void)out_size; (void)ws_size;
    const float* x    = (const float*)d_in[0];
    const int*   ei   = (const int*)d_in[1];
    const int*   bidx = (const int*)d_in[2];
    const float* tw   = (const float*)d_in[3];
    const float* W1 = (const float*)d_in[4],  *b1 = (const float*)d_in[5],  *g1 = (const float*)d_in[6];
    const float* be1= (const float*)d_in[7],  *rm1= (const float*)d_in[8],  *rv1= (const float*)d_in[9];
    const float* W2 = (const float*)d_in[10], *b2 = (const float*)d_in[11], *g2 = (const float*)d_in[12];
    const float* be2= (const float*)d_in[13], *rm2= (const float*)d_in[14], *rv2= (const float*)d_in[15];
    const float* W3 = (const float*)d_in[16], *b3 = (const float*)d_in[17], *g3 = (const float*)d_in[18];
    const float* be3= (const float*)d_in[19], *rm3= (const float*)d_in[20], *rv3= (const float*)d_in[21];
    const float* linW = (const float*)d_in[22], *linb = (const float*)d_in[23];
    float* out = (float*)d_out;

    char* w = (char*)d_ws;
    auto take = [&](size_t bytes) { char* r = w; w += (bytes + 255) & ~(size_t)255; return r; };
    int*   kecnt = (int*)take(16);
    int*   knt   = (int*)take((size_t)BB * 4);
    unsigned char* kf = (unsigned char*)take(NN);
    int*   nslot = (int*)take((size_t)NN * 4);
    float* degs  = (float*)take((size_t)KSLOTS * 4);
    float2* h0s  = (float2*)take((size_t)KSLOTS * 8);
    int*   kedge = (int*)take((size_t)EMAXE * 8);
    float* hY    = (float*)take((size_t)KSLOTS * FD * 4);
    float* hYB   = (float*)take((size_t)KSLOTS * FD * 4);
    // ~12.7 MB total

    k_scorekeep<<<BB, 256, 0, stream>>>((const float2*)x, bidx, tw, kf, nslot, knt, degs, h0s, kecnt);
    k_edges<<<(EE + 255) / 256, 256, 0, stream>>>(ei, kf, nslot, degs, kedge, kecnt);
    k_tail1<<<BB, 256, 0, stream>>>(degs, h0s, kedge, kecnt, knt,
                                    W1, b1, g1, be1, rm1, rv1, W2, hY);
    k_tail2<<<BB, 256, 0, stream>>>(degs, kedge, kecnt, knt, hY,
                                    b2, g2, be2, rm2, rv2, W3, hYB);
    k_tail3<<<BB, 256, 0, stream>>>(degs, kedge, kecnt, knt, hYB,
                                    b3, g3, be3, rm3, rv3, linW, linb, out);
}

// Round 7
// 142.813 us; speedup vs baseline: 2.3612x; 1.0461x over previous
//
#include <hip/hip_runtime.h>

#define NN 100000
#define BB 64
#define EE 1600000
#define FD 128
#define SLOTC 64                 // per-graph kept-row capacity (actual keep count: ~1)
#define KSLOTS (BB * SLOTC)
#define EMAXE (1 << 20)          // kedge capacity (actual: ~0-2)
#define NWORDS ((NN + 31) / 32)  // 3125 words of keep bits

// K0: segment starts (kills binary search), zero keep-bits, kecnt=0.
__global__ void k_starts(const int* __restrict__ bidx, int* __restrict__ starts,
                         unsigned* __restrict__ kfbits, int* __restrict__ kecnt) {
    int gt = blockIdx.x * 256 + threadIdx.x, G = gridDim.x * 256;
    if (gt == 0) *kecnt = 0;
    for (int i = gt; i <= NN; i += G) {
        if (i == 0) {
            int c = bidx[0];
            for (int v = 0; v <= c; v++) starts[v] = 0;
        } else if (i == NN) {
            int a = bidx[NN - 1];
            for (int v = a + 1; v <= BB; v++) starts[v] = NN;
        } else {
            int a = bidx[i - 1], c = bidx[i];
            for (int v = a + 1; v <= c; v++) starts[v] = i;
        }
    }
    for (int w = gt; w < NWORDS; w += G) kfbits[w] = 0u;
}

// K1: one block per graph. 3 passes: (1) max logit m, (2) S=sum exp(l-m),
// (3) keep test using thr=min(1/S-TOL, 0.1)  [max score == 1/S since score is
// monotone in logit and max e = exp(m-m) = 1], slot alloc, h0/deg init.
__global__ __launch_bounds__(256) void k_scorekeep(
    const float2* __restrict__ x, const int* __restrict__ starts,
    const float* __restrict__ tw,
    unsigned* __restrict__ kfbits, int* __restrict__ nslot,
    int* __restrict__ knt, float* __restrict__ degs, float2* __restrict__ h0s)
{
    __shared__ float red[256];
    __shared__ int   klist[SLOTC];
    __shared__ int   lcnt;
    __shared__ float shv;
    int b = blockIdx.x, tid = threadIdx.x;
    if (tid == 0) lcnt = 0;
    int s0 = starts[b], e0 = starts[b + 1], L = e0 - s0;
    float w0 = tw[0], w1 = tw[1];

    // pass 1: max logit
    float mx = -3.4028235e38f;
    for (int j = tid; j < L; j += 256) {
        float2 v = x[s0 + j];
        mx = fmaxf(mx, v.x * w0 + v.y * w1);
    }
    red[tid] = mx; __syncthreads();
    for (int s = 128; s > 0; s >>= 1) { if (tid < s) red[tid] = fmaxf(red[tid], red[tid + s]); __syncthreads(); }
    if (tid == 0) shv = red[0];
    __syncthreads();
    float m = shv;

    // pass 2: S = sum exp(l - m)
    float sm = 0.f;
    for (int j = tid; j < L; j += 256) {
        float2 v = x[s0 + j];
        sm += expf(v.x * w0 + v.y * w1 - m);
    }
    red[tid] = sm; __syncthreads();
    for (int s = 128; s > 0; s >>= 1) { if (tid < s) red[tid] += red[tid + s]; __syncthreads(); }
    if (tid == 0) shv = red[0];
    __syncthreads();
    float S = shv;
    float thr = fminf(1.0f / S - 1e-7f, 0.1f);

    // pass 3: keep test + slot claim
    for (int j = tid; j < L; j += 256) {
        float2 v = x[s0 + j];
        float sc = expf(v.x * w0 + v.y * w1 - m) / S;
        if (sc > thr) {
            int l = atomicAdd(&lcnt, 1);
            if (l < SLOTC) klist[l] = j;
        }
    }
    __syncthreads();
    int nk = lcnt; if (nk > SLOTC) nk = SLOTC;
    if (tid == 0) knt[b] = nk;
    for (int l = tid; l < nk; l += 256) {
        int i = s0 + klist[l];
        float2 v = x[i];
        float sc = expf(v.x * w0 + v.y * w1 - m) / S;
        int slot = b * SLOTC + l;
        atomicOr(&kfbits[i >> 5], 1u << (i & 31));
        nslot[i] = slot;
        degs[slot] = 1.0f;                     // self-loop
        h0s[slot] = make_float2(v.x * sc, v.y * sc);
    }
}

// K2: edge scan, 4 edges/thread; keep-bit gathers hit a 12.5 KB L1-resident
// bitmap; dst id + dst bit only probed when src kept (p ~ 6e-4).
__global__ void k_edges(const int4* __restrict__ src4, const int* __restrict__ ei,
                        const unsigned* __restrict__ kfbits, const int* __restrict__ nslot,
                        float* __restrict__ degs, int* __restrict__ kedge,
                        int* __restrict__ kecnt) {
    int t = blockIdx.x * 256 + threadIdx.x;
    if (t * 4 >= EE) return;
    int4 s4 = src4[t];
    int ss[4] = {s4.x, s4.y, s4.z, s4.w};
    #pragma unroll
    for (int q = 0; q < 4; q++) {
        int s = ss[q];
        if ((kfbits[s >> 5] >> (s & 31)) & 1u) {
            int d = ei[EE + t * 4 + q];
            if ((kfbits[d >> 5] >> (d & 31)) & 1u) {
                int ds = nslot[d];
                atomicAdd(&degs[ds], 1.0f);
                int idx = atomicAdd(kecnt, 1);
                if (idx < EMAXE) { kedge[2 * idx] = nslot[s]; kedge[2 * idx + 1] = ds; }
            }
        }
    }
}

// T1: per-graph: layer-1 agg (2-wide) + node(BN/ReLU) in LDS + mm2 -> hY
__global__ __launch_bounds__(256) void k_tail1(
    const float* __restrict__ degs, const float2* __restrict__ h0s,
    const int* __restrict__ kedge, const int* __restrict__ kecnt,
    const int* __restrict__ knt,
    const float* __restrict__ W1, const float* __restrict__ b1,
    const float* __restrict__ g1, const float* __restrict__ be1,
    const float* __restrict__ rm1, const float* __restrict__ rv1,
    const float* __restrict__ W2, float* __restrict__ hY)
{
    __shared__ float ftile[SLOTC * FD];
    __shared__ float2 psl[SLOTC];
    __shared__ int keS, nkS;
    int b = blockIdx.x, tid = threadIdx.x;
    if (tid == 0) { int k = *kecnt; keS = k > EMAXE ? EMAXE : k; nkS = knt[b]; }
    for (int j = tid; j < SLOTC; j += 256) psl[j] = make_float2(0.f, 0.f);
    __syncthreads();
    int ke = keS, nk = nkS;
    for (int t = tid; t < ke; t += 256) {
        int d = kedge[2 * t + 1];
        if ((d >> 6) == b) {
            int s = kedge[2 * t], ld = d & 63;
            float nm = rsqrtf(degs[s]) * rsqrtf(degs[d]);
            float2 h = h0s[s];
            atomicAdd(&psl[ld].x, nm * h.x);
            atomicAdd(&psl[ld].y, nm * h.y);
        }
    }
    __syncthreads();
    for (int j = tid; j < nk * FD; j += 256) {
        int ld = j >> 7, f = j & 127, slot = b * SLOTC + ld;
        float di = rsqrtf(degs[slot]), d2 = di * di;
        float2 h = h0s[slot];
        float a0 = psl[ld].x + d2 * h.x;
        float a1 = psl[ld].y + d2 * h.y;
        float v = a0 * W1[f] + a1 * W1[FD + f] + b1[f];
        v = fmaxf(v, 0.f);
        v = (v - rm1[f]) * rsqrtf(rv1[f] + 1e-5f) * g1[f] + be1[f];
        ftile[j] = v;
    }
    __syncthreads();
    for (int j = tid; j < nk * FD; j += 256) {
        int ld = j >> 7, f = j & 127;
        const float* xr = ftile + ld * FD;
        float acc = 0.f;
        #pragma unroll 8
        for (int k = 0; k < FD; k++) acc += xr[k] * W2[k * FD + f];
        hY[(b * SLOTC + ld) * FD + f] = acc;
    }
}

// T2: per-graph: scatter(hY) + bn2 in LDS + mm3 -> hYB
__global__ __launch_bounds__(256) void k_tail2(
    const float* __restrict__ degs, const int* __restrict__ kedge,
    const int* __restrict__ kecnt, const int* __restrict__ knt,
    const float* __restrict__ hY,
    const float* __restrict__ b2, const float* __restrict__ g2,
    const float* __restrict__ be2, const float* __restrict__ rm2,
    const float* __restrict__ rv2,
    const float* __restrict__ W3, float* __restrict__ hYB)
{
    __shared__ float ftile[SLOTC * FD];
    __shared__ int keS, nkS;
    int b = blockIdx.x, tid = threadIdx.x;
    if (tid == 0) { int k = *kecnt; keS = k > EMAXE ? EMAXE : k; nkS = knt[b]; }
    __syncthreads();
    int ke = keS, nk = nkS;
    for (int j = tid; j < nk * FD; j += 256) ftile[j] = 0.f;
    __syncthreads();
    for (long long idx = tid; idx < (long long)ke * FD; idx += 256) {
        int e = (int)(idx >> 7), f = (int)(idx & 127);
        int d = kedge[2 * e + 1];
        if ((d >> 6) == b) {
            int s = kedge[2 * e];
            float nm = rsqrtf(degs[s]) * rsqrtf(degs[d]);
            atomicAdd(&ftile[(d & 63) * FD + f], nm * hY[s * FD + f]);
        }
    }
    __syncthreads();
    for (int j = tid; j < nk * FD; j += 256) {
        int ld = j >> 7, f = j & 127, slot = b * SLOTC + ld;
        float di = rsqrtf(degs[slot]);
        float v = ftile[j] + di * di * hY[slot * FD + f] + b2[f];
        v = fmaxf(v, 0.f);
        v = (v - rm2[f]) * rsqrtf(rv2[f] + 1e-5f) * g2[f] + be2[f];
        ftile[j] = v;
    }
    __syncthreads();
    for (int j = tid; j < nk * FD; j += 256) {
        int ld = j >> 7, f = j & 127;
        const float* xr = ftile + ld * FD;
        float acc = 0.f;
        #pragma unroll 8
        for (int k = 0; k < FD; k++) acc += xr[k] * W3[k * FD + f];
        hYB[(b * SLOTC + ld) * FD + f] = acc;
    }
}

// T3: per-graph: scatter(hYB) + bn3 + max-pool + linear + log_softmax -> out
__global__ __launch_bounds__(256) void k_tail3(
    const float* __restrict__ degs, const int* __restrict__ kedge,
    const int* __restrict__ kecnt, const int* __restrict__ knt,
    const float* __restrict__ hYB,
    const float* __restrict__ b3, const float* __restrict__ g3,
    const float* __restrict__ be3, const float* __restrict__ rm3,
    const float* __restrict__ rv3,
    const float* __restrict__ linW, const float* __restrict__ linb,
    float* __restrict__ out)
{
    __shared__ float ftile[SLOTC * FD];
    __shared__ float poolv[FD];
    __shared__ int keS, nkS;
    int b = blockIdx.x, tid = threadIdx.x;
    if (tid == 0) { int k = *kecnt; keS = k > EMAXE ? EMAXE : k; nkS = knt[b]; }
    __syncthreads();
    int ke = keS, nk = nkS;
    for (int j = tid; j < nk * FD; j += 256) ftile[j] = 0.f;
    __syncthreads();
    for (long long idx = tid; idx < (long long)ke * FD; idx += 256) {
        int e = (int)(idx >> 7), f = (int)(idx & 127);
        int d = kedge[2 * e + 1];
        if ((d >> 6) == b) {
            int s = kedge[2 * e];
            float nm = rsqrtf(degs[s]) * rsqrtf(degs[d]);
            atomicAdd(&ftile[(d & 63) * FD + f], nm * hYB[s * FD + f]);
        }
    }
    __syncthreads();
    for (int j = tid; j < nk * FD; j += 256) {
        int ld = j >> 7, f = j & 127, slot = b * SLOTC + ld;
        float di = rsqrtf(degs[slot]);
        float v = ftile[j] + di * di * hYB[slot * FD + f] + b3[f];
        v = fmaxf(v, 0.f);
        v = (v - rm3[f]) * rsqrtf(rv3[f] + 1e-5f) * g3[f] + be3[f];
        ftile[j] = v;
    }
    __syncthreads();
    for (int f = tid; f < FD; f += 256) {
        float mx = -3.4028235e38f;
        for (int ld = 0; ld < nk; ld++) mx = fmaxf(mx, ftile[ld * FD + f]);
        poolv[f] = mx;
    }
    __syncthreads();
    if (tid == 0) {
        float z0 = linb[0], z1 = linb[1], z2 = linb[2];
        for (int f = 0; f < FD; f++) {
            float pv = poolv[f];
            z0 += pv * linW[f * 3 + 0];
            z1 += pv * linW[f * 3 + 1];
            z2 += pv * linW[f * 3 + 2];
        }
        float m = fmaxf(z0, fmaxf(z1, z2));
        float l = m + logf(expf(z0 - m) + expf(z1 - m) + expf(z2 - m));
        out[b * 3 + 0] = z0 - l;
        out[b * 3 + 1] = z1 - l;
        out[b * 3 + 2] = z2 - l;
    }
}

extern "C" void kernel_launch(void* const* d_in, const int* in_sizes, int n_in,
                              void* d_out, int out_size, void* d_ws, size_t ws_size,
                              hipStream_t stream) {
    (void)in_sizes; (void)n_in; (void)out_size; (void)ws_size;
    const float* x    = (const float*)d_in[0];
    const int*   ei   = (const int*)d_in[1];
    const int*   bidx = (const int*)d_in[2];
    const float* tw   = (const float*)d_in[3];
    const float* W1 = (const float*)d_in[4],  *b1 = (const float*)d_in[5],  *g1 = (const float*)d_in[6];
    const float* be1= (const float*)d_in[7],  *rm1= (const float*)d_in[8],  *rv1= (const float*)d_in[9];
    const float* W2 = (const float*)d_in[10], *b2 = (const float*)d_in[11], *g2 = (const float*)d_in[12];
    const float* be2= (const float*)d_in[13], *rm2= (const float*)d_in[14], *rv2= (const float*)d_in[15];
    const float* W3 = (const float*)d_in[16], *b3 = (const float*)d_in[17], *g3 = (const float*)d_in[18];
    const float* be3= (const float*)d_in[19], *rm3= (const float*)d_in[20], *rv3= (const float*)d_in[21];
    const float* linW = (const float*)d_in[22], *linb = (const float*)d_in[23];
    float* out = (float*)d_out;

    char* w = (char*)d_ws;
    auto take = [&](size_t bytes) { char* r = w; w += (bytes + 255) & ~(size_t)255; return r; };
    int*      kecnt  = (int*)take(16);
    int*      starts = (int*)take((size_t)(BB + 1) * 4);
    int*      knt    = (int*)take((size_t)BB * 4);
    unsigned* kfbits = (unsigned*)take((size_t)NWORDS * 4);
    int*      nslot  = (int*)take((size_t)NN * 4);
    float*    degs   = (float*)take((size_t)KSLOTS * 4);
    float2*   h0s    = (float2*)take((size_t)KSLOTS * 8);
    int*      kedge  = (int*)take((size_t)EMAXE * 8);
    float*    hY     = (float*)take((size_t)KSLOTS * FD * 4);
    float*    hYB    = (float*)take((size_t)KSLOTS * FD * 4);

    k_starts<<<392, 256, 0, stream>>>(bidx, starts, kfbits, kecnt);
    k_scorekeep<<<BB, 256, 0, stream>>>((const float2*)x, starts, tw,
                                        kfbits, nslot, knt, degs, h0s);
    k_edges<<<(EE / 4 + 255) / 256, 256, 0, stream>>>((const int4*)ei, ei, kfbits,
                                                      nslot, degs, kedge, kecnt);
    k_tail1<<<BB, 256, 0, stream>>>(degs, h0s, kedge, kecnt, knt,
                                    W1, b1, g1, be1, rm1, rv1, W2, hY);
    k_tail2<<<BB, 256, 0, stream>>>(degs, kedge, kecnt, knt, hY,
                                    b2, g2, be2, rm2, rv2, W3, hYB);
    k_tail3<<<BB, 256, 0, stream>>>(degs, kedge, kecnt, knt, hYB,
                                    b3, g3, be3, rm3, rv3, linW, linb, out);
}

// Round 8
// 141.433 us; speedup vs baseline: 2.3843x; 1.0098x over previous
//
#include <hip/hip_runtime.h>

#define NN 100000
#define BB 64
#define EE 1600000
#define FD 128
#define SLOTC 64                 // per-graph kept-row capacity (actual: ~1)
#define KSLOTS (BB * SLOTC)
#define EMAXE (1 << 20)
#define NWORDS (NN / 32)         // 3125 exactly (100000 % 32 == 0)
#define STR 391                  // ceil(NN/256)

// parallel lower_bound over sorted bidx: first idx in [0,NN] with bidx[idx]>=v.
// All 256 threads participate (contains __syncthreads).
__device__ __forceinline__ int plower(const int* __restrict__ bidx, int v,
                                      int tid, int* ired) {
    int p = tid * STR;                       // max 99705 < NN
    int val = bidx[p];
    ired[tid] = (val < v) ? tid : -1;
    __syncthreads();
    for (int s = 128; s > 0; s >>= 1) { if (tid < s) ired[tid] = max(ired[tid], ired[tid + s]); __syncthreads(); }
    int t0 = ired[0];
    __syncthreads();
    if (t0 < 0) return 0;
    int lo = t0 * STR;                       // bidx[lo] < v
    int hi = lo + STR; if (hi > NN) hi = NN; // answer in (lo, hi]
    int ans = hi;
    for (int q = lo + 1 + tid; q < hi; q += 256) {
        if (bidx[q] >= v) { ans = q; break; }// per-thread probes ascending
    }
    ired[tid] = ans;
    __syncthreads();
    for (int s = 128; s > 0; s >>= 1) { if (tid < s) ired[tid] = min(ired[tid], ired[tid + s]); __syncthreads(); }
    int r = ired[0];
    __syncthreads();
    return r;
}

// K1: one block per graph. Parallel segment search; clear own kfbits slice;
// 3 passes: max logit m, S=sum exp, keep test (thr = min(1/S - TOL, 0.1),
// since max score == 1/S); slot alloc; h0/deg init.
__global__ __launch_bounds__(256) void k_scorekeep(
    const float2* __restrict__ x, const int* __restrict__ bidx,
    const float* __restrict__ tw,
    unsigned* __restrict__ kfbits, int* __restrict__ nslot,
    int* __restrict__ knt, float* __restrict__ degs, float2* __restrict__ h0s,
    int* __restrict__ kecnt)
{
    __shared__ int   ired[256];
    __shared__ float red[256];
    __shared__ int   klist[SLOTC];
    __shared__ int   lcnt;
    __shared__ float shv;
    int b = blockIdx.x, tid = threadIdx.x;
    if (tid == 0) { lcnt = 0; if (b == 0) { kecnt[0] = 0; kecnt[1] = 0; } }
    int s0 = plower(bidx, b, tid, ired);
    int e0 = plower(bidx, b + 1, tid, ired);
    int L = e0 - s0;
    float w0 = tw[0], w1 = tw[1];

    // clear my slice of keep-bits. Interior words: plain store (no other graph
    // owns any bit). Boundary words: atomicAnd own-bits mask (disjoint vs
    // neighbors' atomicAnd/atomicOr -> commutes).
    if (L > 0) {
        int wlo = s0 >> 5, whi = (e0 - 1) >> 5;
        for (int w = wlo + tid; w <= whi; w += 256) {
            unsigned mask = 0xFFFFFFFFu;
            if (w == wlo) mask &= (0xFFFFFFFFu << (s0 & 31));
            if (w == whi) mask &= (0xFFFFFFFFu >> (31 - ((e0 - 1) & 31)));
            if (mask == 0xFFFFFFFFu) kfbits[w] = 0u;
            else atomicAnd(&kfbits[w], ~mask);
        }
    }

    // pass 1: max logit
    float mx = -3.4028235e38f;
    for (int j = tid; j < L; j += 256) {
        float2 v = x[s0 + j];
        mx = fmaxf(mx, v.x * w0 + v.y * w1);
    }
    red[tid] = mx; __syncthreads();
    for (int s = 128; s > 0; s >>= 1) { if (tid < s) red[tid] = fmaxf(red[tid], red[tid + s]); __syncthreads(); }
    if (tid == 0) shv = red[0];
    __syncthreads();
    float m = shv;

    // pass 2: S = sum exp(l - m)
    float sm = 0.f;
    for (int j = tid; j < L; j += 256) {
        float2 v = x[s0 + j];
        sm += expf(v.x * w0 + v.y * w1 - m);
    }
    red[tid] = sm; __syncthreads();
    for (int s = 128; s > 0; s >>= 1) { if (tid < s) red[tid] += red[tid + s]; __syncthreads(); }
    if (tid == 0) shv = red[0];
    __syncthreads();
    float S = shv;
    float thr = fminf(1.0f / S - 1e-7f, 0.1f);

    // pass 3: keep test + slot claim
    for (int j = tid; j < L; j += 256) {
        float2 v = x[s0 + j];
        float sc = expf(v.x * w0 + v.y * w1 - m) / S;
        if (sc > thr) {
            int l = atomicAdd(&lcnt, 1);
            if (l < SLOTC) klist[l] = j;
        }
    }
    __syncthreads();
    int nk = lcnt; if (nk > SLOTC) nk = SLOTC;
    if (tid == 0) knt[b] = nk;
    for (int l = tid; l < nk; l += 256) {
        int i = s0 + klist[l];
        float2 v = x[i];
        float sc = expf(v.x * w0 + v.y * w1 - m) / S;
        int slot = b * SLOTC + l;
        atomicOr(&kfbits[i >> 5], 1u << (i & 31));
        nslot[i] = slot;
        degs[slot] = 1.0f;                   // self-loop
        h0s[slot] = make_float2(v.x * sc, v.y * sc);
    }
}

// K2: edge scan, 4 edges/thread; 12.5 KB bitmap L1-resident; dst probed only
// on src-kept (p ~ 6e-4). Counts total and cross-graph kept edges.
__global__ void k_edges(const int4* __restrict__ src4, const int* __restrict__ ei,
                        const unsigned* __restrict__ kfbits, const int* __restrict__ nslot,
                        float* __restrict__ degs, int* __restrict__ kedge,
                        int* __restrict__ kecnt) {
    int t = blockIdx.x * 256 + threadIdx.x;
    if (t * 4 >= EE) return;
    int4 s4 = src4[t];
    int ss[4] = {s4.x, s4.y, s4.z, s4.w};
    #pragma unroll
    for (int q = 0; q < 4; q++) {
        int s = ss[q];
        if ((kfbits[s >> 5] >> (s & 31)) & 1u) {
            int d = ei[EE + t * 4 + q];
            if ((kfbits[d >> 5] >> (d & 31)) & 1u) {
                int ds = nslot[d], sl = nslot[s];
                atomicAdd(&degs[ds], 1.0f);
                int idx = atomicAdd(&kecnt[0], 1);
                if (idx < EMAXE) { kedge[2 * idx] = sl; kedge[2 * idx + 1] = ds; }
                if ((sl >> 6) != (ds >> 6)) atomicAdd(&kecnt[1], 1);
            }
        }
    }
}

// K3: one block per graph. If no cross-graph kept edges (uniform branch):
// full 3-layer GCN + BN + pool + linear + log_softmax in LDS -> out.
// Else: layer-1 + mm2 -> hY (generic tail1), slow path finishes in K4.
__global__ __launch_bounds__(256) void k_tail_main(
    const float* __restrict__ degs, const float2* __restrict__ h0s,
    const int* __restrict__ kedge, const int* __restrict__ kecnt,
    const int* __restrict__ knt,
    const float* __restrict__ W1, const float* __restrict__ b1,
    const float* __restrict__ g1, const float* __restrict__ be1,
    const float* __restrict__ rm1, const float* __restrict__ rv1,
    const float* __restrict__ W2, const float* __restrict__ b2,
    const float* __restrict__ g2, const float* __restrict__ be2,
    const float* __restrict__ rm2, const float* __restrict__ rv2,
    const float* __restrict__ W3, const float* __restrict__ b3,
    const float* __restrict__ g3, const float* __restrict__ be3,
    const float* __restrict__ rm3, const float* __restrict__ rv3,
    const float* __restrict__ linW, const float* __restrict__ linb,
    float* __restrict__ hY, float* __restrict__ out)
{
    __shared__ float tileA[SLOTC * FD];      // 32 KB
    __shared__ float tileB[SLOTC * FD];      // 32 KB
    __shared__ float2 psl[SLOTC];
    __shared__ float poolv[FD];
    __shared__ int keS;
    int b = blockIdx.x, tid = threadIdx.x;
    if (tid == 0) { int k = kecnt[0]; keS = k > EMAXE ? EMAXE : k; }
    for (int j = tid; j < SLOTC; j += 256) psl[j] = make_float2(0.f, 0.f);
    __syncthreads();
    int ke = keS, nk = knt[b], cross = kecnt[1];

    // layer-1 edge agg (2-wide)
    for (int t = tid; t < ke; t += 256) {
        int d = kedge[2 * t + 1];
        if ((d >> 6) == b) {
            int s = kedge[2 * t];
            float nm = rsqrtf(degs[s]) * rsqrtf(degs[d]);
            float2 h = h0s[s];
            atomicAdd(&psl[d & 63].x, nm * h.x);
            atomicAdd(&psl[d & 63].y, nm * h.y);
        }
    }
    __syncthreads();
    // layer-1 node -> tileA = h1
    for (int j = tid; j < nk * FD; j += 256) {
        int ld = j >> 7, f = j & 127, slot = b * SLOTC + ld;
        float di = rsqrtf(degs[slot]), d2 = di * di;
        float2 h = h0s[slot];
        float a0 = psl[ld].x + d2 * h.x;
        float a1 = psl[ld].y + d2 * h.y;
        float v = a0 * W1[f] + a1 * W1[FD + f] + b1[f];
        v = fmaxf(v, 0.f);
        v = (v - rm1[f]) * rsqrtf(rv1[f] + 1e-5f) * g1[f] + be1[f];
        tileA[j] = v;
    }
    __syncthreads();
    // mm2: tileB = tileA @ W2
    for (int j = tid; j < nk * FD; j += 256) {
        int ld = j >> 7, f = j & 127;
        const float* xr = tileA + ld * FD;
        float acc = 0.f;
        #pragma unroll 8
        for (int k = 0; k < FD; k++) acc += xr[k] * W2[k * FD + f];
        tileB[j] = acc;
    }
    __syncthreads();
    if (cross != 0) {                        // generic path: hand off to K4
        for (int j = tid; j < nk * FD; j += 256) {
            int ld = j >> 7, f = j & 127;
            hY[(b * SLOTC + ld) * FD + f] = tileB[j];
        }
        return;
    }
    // ---- fast path: all kept edges are intra-graph; finish in LDS ----
    // layer-2 scatter (LDS)
    for (int j = tid; j < nk * FD; j += 256) tileA[j] = 0.f;
    __syncthreads();
    for (long long idx = tid; idx < (long long)ke * FD; idx += 256) {
        int e = (int)(idx >> 7), f = (int)(idx & 127);
        int d = kedge[2 * e + 1];
        if ((d >> 6) == b) {
            int s = kedge[2 * e];            // cross==0 => s in graph b
            float nm = rsqrtf(degs[s]) * rsqrtf(degs[d]);
            atomicAdd(&tileA[(d & 63) * FD + f], nm * tileB[(s & 63) * FD + f]);
        }
    }
    __syncthreads();
    // bn2 -> tileA = h2
    for (int j = tid; j < nk * FD; j += 256) {
        int ld = j >> 7, f = j & 127, slot = b * SLOTC + ld;
        float di = rsqrtf(degs[slot]);
        float v = tileA[j] + di * di * tileB[j] + b2[f];
        v = fmaxf(v, 0.f);
        v = (v - rm2[f]) * rsqrtf(rv2[f] + 1e-5f) * g2[f] + be2[f];
        tileA[j] = v;
    }
    __syncthreads();
    // mm3: tileB = tileA @ W3
    for (int j = tid; j < nk * FD; j += 256) {
        int ld = j >> 7, f = j & 127;
        const float* xr = tileA + ld * FD;
        float acc = 0.f;
        #pragma unroll 8
        for (int k = 0; k < FD; k++) acc += xr[k] * W3[k * FD + f];
        tileB[j] = acc;
    }
    __syncthreads();
    // layer-3 scatter (LDS)
    for (int j = tid; j < nk * FD; j += 256) tileA[j] = 0.f;
    __syncthreads();
    for (long long idx = tid; idx < (long long)ke * FD; idx += 256) {
        int e = (int)(idx >> 7), f = (int)(idx & 127);
        int d = kedge[2 * e + 1];
        if ((d >> 6) == b) {
            int s = kedge[2 * e];
            float nm = rsqrtf(degs[s]) * rsqrtf(degs[d]);
            atomicAdd(&tileA[(d & 63) * FD + f], nm * tileB[(s & 63) * FD + f]);
        }
    }
    __syncthreads();
    // bn3 -> tileA = h3
    for (int j = tid; j < nk * FD; j += 256) {
        int ld = j >> 7, f = j & 127, slot = b * SLOTC + ld;
        float di = rsqrtf(degs[slot]);
        float v = tileA[j] + di * di * tileB[j] + b3[f];
        v = fmaxf(v, 0.f);
        v = (v - rm3[f]) * rsqrtf(rv3[f] + 1e-5f) * g3[f] + be3[f];
        tileA[j] = v;
    }
    __syncthreads();
    // pool + linear + log_softmax
    for (int f = tid; f < FD; f += 256) {
        float mx = -3.4028235e38f;
        for (int ld = 0; ld < nk; ld++) mx = fmaxf(mx, tileA[ld * FD + f]);
        poolv[f] = mx;
    }
    __syncthreads();
    if (tid == 0) {
        float z0 = linb[0], z1 = linb[1], z2 = linb[2];
        for (int f = 0; f < FD; f++) {
            float pv = poolv[f];
            z0 += pv * linW[f * 3 + 0];
            z1 += pv * linW[f * 3 + 1];
            z2 += pv * linW[f * 3 + 2];
        }
        float m = fmaxf(z0, fmaxf(z1, z2));
        float l = m + logf(expf(z0 - m) + expf(z1 - m) + expf(z2 - m));
        out[b * 3 + 0] = z0 - l;
        out[b * 3 + 1] = z1 - l;
        out[b * 3 + 2] = z2 - l;
    }
}

// K4: generic fallback (cross-graph kept edges exist). Fuses tail2+tail3:
// foreign hYB rows are recomputed on demand from hY (stable since K3 ended).
// Early-exits (~noop) when cross == 0.
__global__ __launch_bounds__(256) void k_tail_slow(
    const float* __restrict__ degs, const int* __restrict__ kedge,
    const int* __restrict__ kecnt, const int* __restrict__ knt,
    const float* __restrict__ hY,
    const float* __restrict__ b2, const float* __restrict__ g2,
    const float* __restrict__ be2, const float* __restrict__ rm2,
    const float* __restrict__ rv2,
    const float* __restrict__ W3, const float* __restrict__ b3,
    const float* __restrict__ g3, const float* __restrict__ be3,
    const float* __restrict__ rm3, const float* __restrict__ rv3,
    const float* __restrict__ linW, const float* __restrict__ linb,
    float* __restrict__ out)
{
    if (kecnt[1] == 0) return;               // fast path already wrote out
    __shared__ float tileA[SLOTC * FD];
    __shared__ float tileB[SLOTC * FD];
    __shared__ float rowt[FD];
    __shared__ float poolv[FD];
    __shared__ int keS;
    int b = blockIdx.x, tid = threadIdx.x;
    if (tid == 0) { int k = kecnt[0]; keS = k > EMAXE ? EMAXE : k; }
    __syncthreads();
    int ke = keS, nk = knt[b];

    // agg2 (global hY gathers)
    for (int j = tid; j < nk * FD; j += 256) tileA[j] = 0.f;
    __syncthreads();
    for (long long idx = tid; idx < (long long)ke * FD; idx += 256) {
        int e = (int)(idx >> 7), f = (int)(idx & 127);
        int d = kedge[2 * e + 1];
        if ((d >> 6) == b) {
            int s = kedge[2 * e];
            float nm = rsqrtf(degs[s]) * rsqrtf(degs[d]);
            atomicAdd(&tileA[(d & 63) * FD + f], nm * hY[s * FD + f]);
        }
    }
    __syncthreads();
    // bn2 -> tileA = h2_own
    for (int j = tid; j < nk * FD; j += 256) {
        int ld = j >> 7, f = j & 127, slot = b * SLOTC + ld;
        float di = rsqrtf(degs[slot]);
        float v = tileA[j] + di * di * hY[slot * FD + f] + b2[f];
        v = fmaxf(v, 0.f);
        v = (v - rm2[f]) * rsqrtf(rv2[f] + 1e-5f) * g2[f] + be2[f];
        tileA[j] = v;
    }
    __syncthreads();
    // mm3 -> tileB = hYB_own
    for (int j = tid; j < nk * FD; j += 256) {
        int ld = j >> 7, f = j & 127;
        const float* xr = tileA + ld * FD;
        float acc = 0.f;
        #pragma unroll 8
        for (int k = 0; k < FD; k++) acc += xr[k] * W3[k * FD + f];
        tileB[j] = acc;
    }
    __syncthreads();
    // scatter3: intra sources from tileB; agg into tileA (h2 dead now)
    for (int j = tid; j < nk * FD; j += 256) tileA[j] = 0.f;
    __syncthreads();
    for (long long idx = tid; idx < (long long)ke * FD; idx += 256) {
        int e = (int)(idx >> 7), f = (int)(idx & 127);
        int d = kedge[2 * e + 1];
        if ((d >> 6) == b) {
            int s = kedge[2 * e];
            if ((s >> 6) == b) {
                float nm = rsqrtf(degs[s]) * rsqrtf(degs[d]);
                atomicAdd(&tileA[(d & 63) * FD + f], nm * tileB[(s & 63) * FD + f]);
            }
        }
    }
    __syncthreads();
    // cross sources: recompute hYB[s] on demand (rare fallback)
    for (int e = 0; e < ke; e++) {
        int d = kedge[2 * e + 1];
        if ((d >> 6) != b) continue;
        int s = kedge[2 * e];
        if ((s >> 6) == b) continue;
        // rowt = h2_s
        float dis = rsqrtf(degs[s]);
        for (int f = tid; f < FD; f += 256) {
            float acc = dis * dis * hY[s * FD + f];
            for (int e2 = 0; e2 < ke; e2++) {
                if (kedge[2 * e2 + 1] == s) {
                    int u = kedge[2 * e2];
                    acc += rsqrtf(degs[u]) * dis * hY[u * FD + f];
                }
            }
            float v = acc + b2[f];
            v = fmaxf(v, 0.f);
            v = (v - rm2[f]) * rsqrtf(rv2[f] + 1e-5f) * g2[f] + be2[f];
            rowt[f] = v;
        }
        __syncthreads();
        float nm = dis * rsqrtf(degs[d]);
        for (int f = tid; f < FD; f += 256) {
            float acc = 0.f;
            #pragma unroll 8
            for (int k = 0; k < FD; k++) acc += rowt[k] * W3[k * FD + f];
            atomicAdd(&tileA[(d & 63) * FD + f], nm * acc);
        }
        __syncthreads();
    }
    // bn3 -> tileA = h3
    for (int j = tid; j < nk * FD; j += 256) {
        int ld = j >> 7, f = j & 127, slot = b * SLOTC + ld;
        float di = rsqrtf(degs[slot]);
        float v = tileA[j] + di * di * tileB[j] + b3[f];
        v = fmaxf(v, 0.f);
        v = (v - rm3[f]) * rsqrtf(rv3[f] + 1e-5f) * g3[f] + be3[f];
        tileA[j] = v;
    }
    __syncthreads();
    for (int f = tid; f < FD; f += 256) {
        float mx = -3.4028235e38f;
        for (int ld = 0; ld < nk; ld++) mx = fmaxf(mx, tileA[ld * FD + f]);
        poolv[f] = mx;
    }
    __syncthreads();
    if (tid == 0) {
        float z0 = linb[0], z1 = linb[1], z2 = linb[2];
        for (int f = 0; f < FD; f++) {
            float pv = poolv[f];
            z0 += pv * linW[f * 3 + 0];
            z1 += pv * linW[f * 3 + 1];
            z2 += pv * linW[f * 3 + 2];
        }
        float m = fmaxf(z0, fmaxf(z1, z2));
        float l = m + logf(expf(z0 - m) + expf(z1 - m) + expf(z2 - m));
        out[b * 3 + 0] = z0 - l;
        out[b * 3 + 1] = z1 - l;
        out[b * 3 + 2] = z2 - l;
    }
}

extern "C" void kernel_launch(void* const* d_in, const int* in_sizes, int n_in,
                              void* d_out, int out_size, void* d_ws, size_t ws_size,
                              hipStream_t stream) {
    (void)in_sizes; (void)n_in; (void)out_size; (void)ws_size;
    const float* x    = (const float*)d_in[0];
    const int*   ei   = (const int*)d_in[1];
    const int*   bidx = (const int*)d_in[2];
    const float* tw   = (const float*)d_in[3];
    const float* W1 = (const float*)d_in[4],  *b1 = (const float*)d_in[5],  *g1 = (const float*)d_in[6];
    const float* be1= (const float*)d_in[7],  *rm1= (const float*)d_in[8],  *rv1= (const float*)d_in[9];
    const float* W2 = (const float*)d_in[10], *b2 = (const float*)d_in[11], *g2 = (const float*)d_in[12];
    const float* be2= (const float*)d_in[13], *rm2= (const float*)d_in[14], *rv2= (const float*)d_in[15];
    const float* W3 = (const float*)d_in[16], *b3 = (const float*)d_in[17], *g3 = (const float*)d_in[18];
    const float* be3= (const float*)d_in[19], *rm3= (const float*)d_in[20], *rv3= (const float*)d_in[21];
    const float* linW = (const float*)d_in[22], *linb = (const float*)d_in[23];
    float* out = (float*)d_out;

    char* w = (char*)d_ws;
    auto take = [&](size_t bytes) { char* r = w; w += (bytes + 255) & ~(size_t)255; return r; };
    int*      kecnt  = (int*)take(16);        // [0]=total kept edges, [1]=cross
    int*      knt    = (int*)take((size_t)BB * 4);
    unsigned* kfbits = (unsigned*)take((size_t)NWORDS * 4);
    int*      nslot  = (int*)take((size_t)NN * 4);
    float*    degs   = (float*)take((size_t)KSLOTS * 4);
    float2*   h0s    = (float2*)take((size_t)KSLOTS * 8);
    int*      kedge  = (int*)take((size_t)EMAXE * 8);
    float*    hY     = (float*)take((size_t)KSLOTS * FD * 4);
    // ~10.7 MB

    k_scorekeep<<<BB, 256, 0, stream>>>((const float2*)x, bidx, tw,
                                        kfbits, nslot, knt, degs, h0s, kecnt);
    k_edges<<<(EE / 4 + 255) / 256, 256, 0, stream>>>((const int4*)ei, ei, kfbits,
                                                      nslot, degs, kedge, kecnt);
    k_tail_main<<<BB, 256, 0, stream>>>(degs, h0s, kedge, kecnt, knt,
                                        W1, b1, g1, be1, rm1, rv1,
                                        W2, b2, g2, be2, rm2, rv2,
                                        W3, b3, g3, be3, rm3, rv3,
                                        linW, linb, hY, out);
    k_tail_slow<<<BB, 256, 0, stream>>>(degs, kedge, kecnt, knt, hY,
                                        b2, g2, be2, rm2, rv2,
                                        W3, b3, g3, be3, rm3, rv3,
                                        linW, linb, out);
}